// Round 1
// baseline (454.242 us; speedup 1.0000x reference)
//
#include <hip/hip_runtime.h>

// ProtoSAE fused: h = BN(ReLU?) no -- h = relu(BN(x@W1^T + b1)); enc = h@W2^T + b2;
// act = f(||enc - proto||^2).  T=8192 tokens, NI=1024, L=128 latents, H=128, P=64.
// Strategy: bf16 MFMA for both GEMMs, fully fused per (token-tile=128, latent) block.

#define NTOK 8192
#define NI   1024
#define NL   128
#define NH   128
#define NP   64
#define BK   64

typedef __bf16 bf16x8 __attribute__((ext_vector_type(8)));
typedef float f32x4 __attribute__((ext_vector_type(4)));

__device__ __forceinline__ unsigned short f2bf(float f) {
  union { float f; unsigned int u; } v; v.f = f;
  const unsigned int u = v.u;
  return (unsigned short)((u + 0x7fffu + ((u >> 16) & 1u)) >> 16);  // RNE
}

// f32 -> bf16 conversion prepass, 8 elems/thread
__global__ void cvt_f32_bf16(const float* __restrict__ in,
                             unsigned short* __restrict__ out, int n8) {
  const int i = blockIdx.x * blockDim.x + threadIdx.x;
  if (i >= n8) return;
  const float4* p = (const float4*)in;
  const float4 a = p[2 * i], b = p[2 * i + 1];
  unsigned short v[8] __attribute__((aligned(16))) = {
      f2bf(a.x), f2bf(a.y), f2bf(a.z), f2bf(a.w),
      f2bf(b.x), f2bf(b.y), f2bf(b.z), f2bf(b.w)};
  ((uint4*)out)[i] = *(const uint4*)v;
}

__device__ __forceinline__ void async16(const void* g, void* l) {
  __builtin_amdgcn_global_load_lds(
      (const __attribute__((address_space(1))) unsigned int*)g,
      (__attribute__((address_space(3))) unsigned int*)l, 16, 0, 0);
}

// Block: 128 tokens x 1 latent. 4 waves as 2x2 (token-half x hcol-half),
// each wave owns a 64x64 h sub-tile (4x4 frags of 16x16x32 MFMA).
__global__ __launch_bounds__(256, 2) void proto_fused(
    const unsigned short* __restrict__ xb,    // [8192][1024] bf16
    const unsigned short* __restrict__ w1b,   // [16384][1024] bf16 (L*H rows, K contig)
    const unsigned short* __restrict__ w2b,   // [128][64][128] bf16 (K=H contig)
    const float* __restrict__ b1,             // [128][128]
    const float* __restrict__ gamma, const float* __restrict__ beta,
    const float* __restrict__ rmean, const float* __restrict__ rvar,
    const float* __restrict__ b2,             // [128][64]
    const float* __restrict__ protos,         // [128][64]
    float* __restrict__ out)                  // [8192][128]
{
  __shared__ __attribute__((aligned(128))) char smem[65536];
  // LDS map (GEMM1): A[buf] at buf*16384 (128x64 bf16), B[buf] at 32768+buf*16384
  // LDS map (epilogue): hs = smem[0..32768) (128x128 bf16), W2s = smem[32768..49152)
  const int tid  = threadIdx.x;
  const int wave = tid >> 6;
  const int lane = tid & 63;
  const int l15  = lane & 15;
  const int l4   = lane >> 4;
  const int wr   = wave >> 1;   // token half (0..1)
  const int wc   = wave & 1;    // hcol half (0..1)
  const int t0   = blockIdx.x * 128;
  const int lat  = blockIdx.y;

  const int srow = lane >> 3;          // row within 8-row staging chunk
  const int scol = (lane & 7) * 8;     // bf16 col within row

  f32x4 acc[4][4] = {};

  auto stage = [&](int buf, int ks) {
    const int k0 = ks * BK;
#pragma unroll
    for (int j = 0; j < 4; ++j) {
      const int row = wave * 32 + j * 8 + srow;     // chunk q = wave*4+j
      async16(xb + (size_t)(t0 + row) * NI + k0 + scol,
              smem + buf * 16384 + (wave * 4 + j) * 1024);
      async16(w1b + (size_t)(lat * NH + row) * NI + k0 + scol,
              smem + 32768 + buf * 16384 + (wave * 4 + j) * 1024);
    }
  };

  int buf = 0;
  stage(0, 0);
  for (int ks = 0; ks < 16; ++ks) {
    __syncthreads();                 // drains vmcnt: buf ready; prev compute done
    if (ks + 1 < 16) stage(buf ^ 1, ks + 1);
    const char* Ab = smem + buf * 16384;
    const char* Bb = smem + 32768 + buf * 16384;
#pragma unroll
    for (int kk = 0; kk < 2; ++kk) {
      const int kbyte = kk * 64 + l4 * 16;   // (kk*32 + l4*8) bf16
      bf16x8 a[4], b[4];
#pragma unroll
      for (int m = 0; m < 4; ++m)
        a[m] = *(const bf16x8*)(Ab + (wr * 64 + m * 16 + l15) * 128 + kbyte);
#pragma unroll
      for (int n = 0; n < 4; ++n)
        b[n] = *(const bf16x8*)(Bb + (wc * 64 + n * 16 + l15) * 128 + kbyte);
#pragma unroll
      for (int m = 0; m < 4; ++m)
#pragma unroll
        for (int n = 0; n < 4; ++n)
          acc[m][n] = __builtin_amdgcn_mfma_f32_16x16x32_bf16(a[m], b[n], acc[m][n], 0, 0, 0);
    }
    buf ^= 1;
  }
  __syncthreads();  // all compute done before overwriting LDS with h / W2

  // ---- epilogue 1: bias + BN(eval) + ReLU, h -> LDS bf16 [128][128] ----
  unsigned short* hs = (unsigned short*)smem;
#pragma unroll
  for (int n = 0; n < 4; ++n) {
    const int hc = wc * 64 + n * 16 + l15;
    const int gi = lat * NH + hc;
    const float sc = gamma[gi] * rsqrtf(rvar[gi] + 1e-5f);
    const float bi = beta[gi] - rmean[gi] * sc;
    const float bb = b1[gi];
#pragma unroll
    for (int m = 0; m < 4; ++m)
#pragma unroll
      for (int r = 0; r < 4; ++r) {
        float v = (acc[m][n][r] + bb) * sc + bi;
        v = v > 0.f ? v : 0.f;
        const int trow = wr * 64 + m * 16 + l4 * 4 + r;   // C/D: row=(l>>4)*4+reg
        hs[trow * NH + hc] = f2bf(v);
      }
  }
  // stage W2[lat]: 64x128 bf16 = 16KB into smem+32768
  {
    const uint4* src = (const uint4*)(w2b + (size_t)lat * NP * NH);
    uint4* dst = (uint4*)(smem + 32768);
#pragma unroll
    for (int i = 0; i < 4; ++i) dst[tid + 256 * i] = src[tid + 256 * i];
  }
  __syncthreads();

  // ---- epilogue 2: enc = h @ W2^T  (M=128, N=64(P), K=128) ----
  // waves split M: wave owns 32 token rows (2 m-frags), all 4 n-frags
  f32x4 acc2[2][4] = {};
  const char* W2s = smem + 32768;
#pragma unroll
  for (int kk = 0; kk < 4; ++kk) {
    const int kbyte = kk * 64 + l4 * 16;
    bf16x8 a[2], b[4];
#pragma unroll
    for (int m = 0; m < 2; ++m)
      a[m] = *(const bf16x8*)((const char*)smem + (wave * 32 + m * 16 + l15) * 256 + kbyte);
#pragma unroll
    for (int n = 0; n < 4; ++n)
      b[n] = *(const bf16x8*)(W2s + (n * 16 + l15) * 256 + kbyte);
#pragma unroll
    for (int m = 0; m < 2; ++m)
#pragma unroll
      for (int n = 0; n < 4; ++n)
        acc2[m][n] = __builtin_amdgcn_mfma_f32_16x16x32_bf16(a[m], b[n], acc2[m][n], 0, 0, 0);
  }

  // ---- epilogue 3: L2 distance to prototypes + log activation ----
  float pb[4], pp[4];
#pragma unroll
  for (int n = 0; n < 4; ++n) {
    const int p = n * 16 + l15;
    pb[n] = b2[lat * NP + p];
    pp[n] = protos[lat * NP + p];
  }
  const float act_scale = 300.0f / logf(10000.0f);
#pragma unroll
  for (int m = 0; m < 2; ++m)
#pragma unroll
    for (int r = 0; r < 4; ++r) {
      float s = 0.f;
#pragma unroll
      for (int n = 0; n < 4; ++n) {
        const float e = acc2[m][n][r] + pb[n] - pp[n];
        s += e * e;
      }
      // sum over P spread across the 16 lanes sharing l4 (masks 1,2,4,8 stay in-group)
      s += __shfl_xor(s, 1);
      s += __shfl_xor(s, 2);
      s += __shfl_xor(s, 4);
      s += __shfl_xor(s, 8);
      if (l15 == 0) {
        const float act = logf((s + 1.0f) / (s + 1e-4f)) * act_scale - 100.0f;
        const int trow = wave * 32 + m * 16 + l4 * 4 + r;
        out[(size_t)(t0 + trow) * NL + lat] = act;
      }
    }
}

extern "C" void kernel_launch(void* const* d_in, const int* in_sizes, int n_in,
                              void* d_out, int out_size, void* d_ws, size_t ws_size,
                              hipStream_t stream) {
  const float* x      = (const float*)d_in[0];
  const float* W1     = (const float*)d_in[1];
  const float* b1     = (const float*)d_in[2];
  const float* gamma  = (const float*)d_in[3];
  const float* beta   = (const float*)d_in[4];
  const float* rmean  = (const float*)d_in[5];
  const float* rvar   = (const float*)d_in[6];
  const float* W2     = (const float*)d_in[7];
  const float* b2     = (const float*)d_in[8];
  const float* protos = (const float*)d_in[9];
  float* out = (float*)d_out;

  // workspace: bf16 copies of x, W1, W2 (50 MB total)
  unsigned short* xb  = (unsigned short*)d_ws;
  unsigned short* w1b = xb + (size_t)NTOK * NI;
  unsigned short* w2b = w1b + (size_t)NL * NH * NI;

  {
    const int n8x = NTOK * NI / 8;            // 1048576
    cvt_f32_bf16<<<(n8x + 255) / 256, 256, 0, stream>>>(x, xb, n8x);
    const int n8w1 = NL * NH * NI / 8;        // 2097152
    cvt_f32_bf16<<<(n8w1 + 255) / 256, 256, 0, stream>>>(W1, w1b, n8w1);
    const int n8w2 = NL * NP * NH / 8;        // 131072
    cvt_f32_bf16<<<(n8w2 + 255) / 256, 256, 0, stream>>>(W2, w2b, n8w2);
  }

  dim3 grid(NTOK / 128, NL);
  proto_fused<<<grid, 256, 0, stream>>>(xb, w1b, w2b, b1, gamma, beta,
                                        rmean, rvar, b2, protos, out);
}

// Round 2
// 324.167 us; speedup vs baseline: 1.4013x; 1.4013x over previous
//
#include <hip/hip_runtime.h>

// ProtoSAE fused: h = relu(BN(x@W1^T + b1)); enc = h@W2^T + b2; act = f(||enc-proto||^2)
// T=8192 tokens, NI=1024, L=128 latents, H=128, P=64. bf16 MFMA for both GEMMs.
// R2: T2 XOR-swizzle on all LDS tiles (pre-swizzled global source for global_load_lds,
//     rule 21) + single-buffered 48 KB LDS -> 3 blocks/CU.

#define NTOK 8192
#define NI   1024
#define NL   128
#define NH   128
#define NP   64
#define BK   64

typedef __bf16 bf16x8 __attribute__((ext_vector_type(8)));
typedef float f32x4 __attribute__((ext_vector_type(4)));

__device__ __forceinline__ unsigned short f2bf(float f) {
  union { float f; unsigned int u; } v; v.f = f;
  const unsigned int u = v.u;
  return (unsigned short)((u + 0x7fffu + ((u >> 16) & 1u)) >> 16);  // RNE
}

__global__ void cvt_f32_bf16(const float* __restrict__ in,
                             unsigned short* __restrict__ out, int n8) {
  const int i = blockIdx.x * blockDim.x + threadIdx.x;
  if (i >= n8) return;
  const float4* p = (const float4*)in;
  const float4 a = p[2 * i], b = p[2 * i + 1];
  unsigned short v[8] __attribute__((aligned(16))) = {
      f2bf(a.x), f2bf(a.y), f2bf(a.z), f2bf(a.w),
      f2bf(b.x), f2bf(b.y), f2bf(b.z), f2bf(b.w)};
  ((uint4*)out)[i] = *(const uint4*)v;
}

__device__ __forceinline__ void async16(const void* g, void* l) {
  __builtin_amdgcn_global_load_lds(
      (const __attribute__((address_space(1))) unsigned int*)g,
      (__attribute__((address_space(3))) unsigned int*)l, 16, 0, 0);
}

// Block: 128 tokens x 1 latent. 4 waves as 2x2 (token-half x hcol-half).
// LDS map: A [0,16K) 128x64 bf16 swz; B [16K,32K); W2s [32K,48K) 64x128 bf16 swz
//          (persistent); epilogue hs [0,32K) 128x128 bf16 swz.
__global__ __launch_bounds__(256, 3) void proto_fused(
    const unsigned short* __restrict__ xb,    // [8192][1024] bf16
    const unsigned short* __restrict__ w1b,   // [16384][1024] bf16
    const unsigned short* __restrict__ w2b,   // [128][64][128] bf16
    const float* __restrict__ b1,
    const float* __restrict__ gamma, const float* __restrict__ beta,
    const float* __restrict__ rmean, const float* __restrict__ rvar,
    const float* __restrict__ b2,
    const float* __restrict__ protos,
    float* __restrict__ out)                  // [8192][128]
{
  __shared__ __attribute__((aligned(128))) char smem[49152];
  const int tid  = threadIdx.x;
  const int wave = tid >> 6;
  const int lane = tid & 63;
  const int l15  = lane & 15;
  const int l4   = lane >> 4;
  const int wr   = wave >> 1;
  const int wc   = wave & 1;
  const int t0   = blockIdx.x * 128;
  const int lat  = blockIdx.y;

  const int srow  = lane >> 3;                   // row within 8-row staging chunk
  const int scol8 = ((lane & 7) ^ srow) * 8;     // SWIZZLED source col (bf16 units):
                                                 // physical chunk lane&7 <- logical chunk ^ (row&7)

  f32x4 acc[4][4] = {};

  // ---- stage W2[lat] once: 64x128 bf16 -> smem+32768, chunk ^= row&15 swizzle ----
#pragma unroll
  for (int i = 0; i < 4; ++i) {
    const int r = wave * 4 + i * 16 + (lane >> 4);     // 0..63
    const int c = (lane & 15) ^ (r & 15);              // logical 16B chunk for this lane
    async16(w2b + (size_t)lat * NP * NH + r * NH + c * 8,
            smem + 32768 + (wave * 64 + i * 256) * 16);
  }

  auto stage = [&](int ks) {
    const int k0 = ks * BK;
#pragma unroll
    for (int j = 0; j < 4; ++j) {
      const int row = wave * 32 + j * 8 + srow;
      async16(xb + (size_t)(t0 + row) * NI + k0 + scol8,
              smem + (wave * 4 + j) * 1024);
      async16(w1b + (size_t)(lat * NH + row) * NI + k0 + scol8,
              smem + 16384 + (wave * 4 + j) * 1024);
    }
  };

  // ---- GEMM1 main loop: single-buffered, 2 barriers/K-step (m97 structure) ----
  stage(0);
  const int rx = l15 & 7;
  for (int ks = 0; ks < 16; ++ks) {
    __syncthreads();                 // vmcnt drained: tile ks (and W2s on ks=0) resident
#pragma unroll
    for (int kk = 0; kk < 2; ++kk) {
      bf16x8 a[4], b[4];
#pragma unroll
      for (int m = 0; m < 4; ++m)
        a[m] = *(const bf16x8*)(smem + (wr * 64 + m * 16 + l15) * 128 +
                                (((kk * 4 + l4) ^ rx) << 4));
#pragma unroll
      for (int n = 0; n < 4; ++n)
        b[n] = *(const bf16x8*)(smem + 16384 + (wc * 64 + n * 16 + l15) * 128 +
                                (((kk * 4 + l4) ^ rx) << 4));
#pragma unroll
      for (int m = 0; m < 4; ++m)
#pragma unroll
        for (int n = 0; n < 4; ++n)
          acc[m][n] = __builtin_amdgcn_mfma_f32_16x16x32_bf16(a[m], b[n], acc[m][n], 0, 0, 0);
    }
    __syncthreads();                 // all reads done before overwrite
    if (ks + 1 < 16) stage(ks + 1);
  }

  // ---- epilogue 1: bias + BN(eval) + ReLU -> hs bf16 [128][128], chunk ^= row&15 ----
#pragma unroll
  for (int n = 0; n < 4; ++n) {
    const int hc = wc * 64 + n * 16 + l15;
    const int gi = lat * NH + hc;
    const float sc = gamma[gi] * rsqrtf(rvar[gi] + 1e-5f);
    const float bi = beta[gi] - rmean[gi] * sc;
    const float bb = b1[gi];
#pragma unroll
    for (int m = 0; m < 4; ++m)
#pragma unroll
      for (int r = 0; r < 4; ++r) {
        float v = (acc[m][n][r] + bb) * sc + bi;
        v = v > 0.f ? v : 0.f;
        const int row = wr * 64 + m * 16 + l4 * 4 + r;
        const int pbyte = row * 256 + (((hc >> 3) ^ (row & 15)) << 4) + (hc & 7) * 2;
        *(unsigned short*)(smem + pbyte) = f2bf(v);
      }
  }
  __syncthreads();

  // ---- epilogue 2: enc = h @ W2^T (M=128, N=64, K=128), swizzled reads ----
  f32x4 acc2[2][4] = {};
#pragma unroll
  for (int kk = 0; kk < 4; ++kk) {
    const int pc = ((kk * 4 + l4) ^ l15) << 4;
    bf16x8 a2[2], bw[4];
#pragma unroll
    for (int m = 0; m < 2; ++m)
      a2[m] = *(const bf16x8*)(smem + (wave * 32 + m * 16 + l15) * 256 + pc);
#pragma unroll
    for (int n = 0; n < 4; ++n)
      bw[n] = *(const bf16x8*)(smem + 32768 + (n * 16 + l15) * 256 + pc);
#pragma unroll
    for (int m = 0; m < 2; ++m)
#pragma unroll
      for (int n = 0; n < 4; ++n)
        acc2[m][n] = __builtin_amdgcn_mfma_f32_16x16x32_bf16(a2[m], bw[n], acc2[m][n], 0, 0, 0);
  }

  // ---- epilogue 3: L2 distance to prototypes + log activation ----
  float pb[4], pp[4];
#pragma unroll
  for (int n = 0; n < 4; ++n) {
    const int p = n * 16 + l15;
    pb[n] = b2[lat * NP + p];
    pp[n] = protos[lat * NP + p];
  }
  const float act_scale = 300.0f / logf(10000.0f);
#pragma unroll
  for (int m = 0; m < 2; ++m)
#pragma unroll
    for (int r = 0; r < 4; ++r) {
      float s = 0.f;
#pragma unroll
      for (int n = 0; n < 4; ++n) {
        const float e = acc2[m][n][r] + pb[n] - pp[n];
        s += e * e;
      }
      s += __shfl_xor(s, 1);
      s += __shfl_xor(s, 2);
      s += __shfl_xor(s, 4);
      s += __shfl_xor(s, 8);
      if (l15 == 0) {
        const float act = logf((s + 1.0f) / (s + 1e-4f)) * act_scale - 100.0f;
        const int trow = wave * 32 + m * 16 + l4 * 4 + r;
        out[(size_t)(t0 + trow) * NL + lat] = act;
      }
    }
}

extern "C" void kernel_launch(void* const* d_in, const int* in_sizes, int n_in,
                              void* d_out, int out_size, void* d_ws, size_t ws_size,
                              hipStream_t stream) {
  const float* x      = (const float*)d_in[0];
  const float* W1     = (const float*)d_in[1];
  const float* b1     = (const float*)d_in[2];
  const float* gamma  = (const float*)d_in[3];
  const float* beta   = (const float*)d_in[4];
  const float* rmean  = (const float*)d_in[5];
  const float* rvar   = (const float*)d_in[6];
  const float* W2     = (const float*)d_in[7];
  const float* b2     = (const float*)d_in[8];
  const float* protos = (const float*)d_in[9];
  float* out = (float*)d_out;

  unsigned short* xb  = (unsigned short*)d_ws;
  unsigned short* w1b = xb + (size_t)NTOK * NI;
  unsigned short* w2b = w1b + (size_t)NL * NH * NI;

  {
    const int n8x = NTOK * NI / 8;
    cvt_f32_bf16<<<(n8x + 255) / 256, 256, 0, stream>>>(x, xb, n8x);
    const int n8w1 = NL * NH * NI / 8;
    cvt_f32_bf16<<<(n8w1 + 255) / 256, 256, 0, stream>>>(W1, w1b, n8w1);
    const int n8w2 = NL * NP * NH / 8;
    cvt_f32_bf16<<<(n8w2 + 255) / 256, 256, 0, stream>>>(W2, w2b, n8w2);
  }

  dim3 grid(NTOK / 128, NL);
  proto_fused<<<grid, 256, 0, stream>>>(xb, w1b, w2b, b1, gamma, beta,
                                        rmean, rvar, b2, protos, out);
}